// Round 4
// baseline (5041.387 us; speedup 1.0000x reference)
//
#include <hip/hip_runtime.h>
#include <hip/hip_bf16.h>

// ---------------- problem shape ----------------
#define TT 64
#define BB 256
#define DD 1024
#define HH 1024
#define G4 4096    // 4*H
#define CHT 16     // xg chunk length (timesteps); 4 chunks cover T=64

typedef __bf16 bf16x8 __attribute__((ext_vector_type(8)));
typedef float  f32x4  __attribute__((ext_vector_type(4)));

// ---------------- static device scratch (no d_ws, no API calls) ----------------
// bf16 stored as unsigned short for safe global-array definition.
__device__ unsigned short g_seq [(size_t)TT * BB * 1024];  // x (bf16) -> layer-1 h seq   32 MB
__device__ unsigned short g_Wih [(size_t)2 * G4 * 1024];   // 16 MB
__device__ unsigned short g_Whh [(size_t)2 * G4 * 1024];   // 16 MB
__device__ unsigned short g_Wfh [(size_t)2 * G4 * 1024];   // 16 MB
__device__ unsigned short g_feat[(size_t)BB * 1024];       // 0.5 MB
__device__ unsigned short g_xg  [(size_t)CHT * BB * G4];   // bf16 gates chunk            32 MB
__device__ unsigned short g_h   [2][(size_t)BB * HH];      // h state ping-pong (bf16)     1 MB
__device__ float          g_featb[(size_t)BB * G4];        // f32 feat@Wfh^T + b           4 MB
__device__ float          g_c   [(size_t)BB * HH];         // f32 cell state               1 MB

__device__ __forceinline__ bf16x8 ld8(const __hip_bfloat16* p) {
    return *reinterpret_cast<const bf16x8*>(p);
}
__device__ __forceinline__ __hip_bfloat16* BP(unsigned short* p) {
    return reinterpret_cast<__hip_bfloat16*>(p);
}
__device__ __forceinline__ const __hip_bfloat16* BPc(const unsigned short* p) {
    return reinterpret_cast<const __hip_bfloat16*>(p);
}

// =============================================================
// f32 -> bf16 conversion into a selected device-global buffer.
// which: 0=g_seq 1=g_Wih 2=g_Whh 3=g_Wfh 4=g_feat. 4 elems/thread.
// =============================================================
__global__ __launch_bounds__(256) void cvt_bf16(int which,
                                                const float* __restrict__ s,
                                                size_t n)
{
    size_t i = ((size_t)blockIdx.x * 256 + threadIdx.x) * 4;
    if (i >= n) return;
    unsigned short* d = (which == 0) ? g_seq
                      : (which == 1) ? g_Wih
                      : (which == 2) ? g_Whh
                      : (which == 3) ? g_Wfh : g_feat;
    float4 v = *reinterpret_cast<const float4*>(s + i);
    __hip_bfloat16* db = BP(d) + i;
    db[0] = __float2bfloat16(v.x);
    db[1] = __float2bfloat16(v.y);
    db[2] = __float2bfloat16(v.z);
    db[3] = __float2bfloat16(v.w);
}

// =============================================================
// bf16 GEMM  C[M,4096] = A[M,1024] @ W[4096,1024]^T  (+ epilogue)
// Block 256 thr (4 waves); block tile 128(m) x 64(n); wave tile 64x32.
// MFMA 16x16x32 bf16 fragment layout (guide m89/m91/m92):
//   A frag: lane reads A[m0 + (lane&15)][k0 + (lane>>4)*8 .. +8]
//   B frag: lane reads W[n0 + (lane&15)][k0 + (lane>>4)*8 .. +8]
//   C/D:    D[m0 + (lane>>4)*4 + r][n0 + (lane&15)]
// FEATB=true : A=g_feat (M=256),     W=g_Wfh+off, C->g_featb f32 (+bias f32)
// FEATB=false: A=g_seq+seq_off (M=4096), W=g_Wih+off, C->g_xg bf16 (+g_featb[m&255])
// =============================================================
template<bool FEATB>
__global__ __launch_bounds__(256) void gemm_k(size_t seq_off, size_t w_off,
                                              const float* __restrict__ bias)
{
    const int tid  = threadIdx.x;
    const int lane = tid & 63, wid = tid >> 6;
    const int row  = lane & 15, quad = lane >> 4;
    const int m_base = blockIdx.y * 128 + (wid >> 1) * 64;
    const int n_base = blockIdx.x * 64  + (wid & 1) * 32;

    const __hip_bfloat16* A = FEATB ? BPc(g_feat) : BPc(g_seq) + seq_off;
    const __hip_bfloat16* W = (FEATB ? BPc(g_Wfh) : BPc(g_Wih)) + w_off;

    f32x4 acc[4][2] = {};
    const __hip_bfloat16* Ap = A + (size_t)(m_base + row) * 1024 + quad * 8;
    const __hip_bfloat16* Wp = W + (size_t)(n_base + row) * 1024 + quad * 8;

    for (int k0 = 0; k0 < 1024; k0 += 32) {
        bf16x8 a[4], b[2];
#pragma unroll
        for (int i = 0; i < 4; ++i) a[i] = ld8(Ap + (size_t)(16 * i) * 1024 + k0);
#pragma unroll
        for (int j = 0; j < 2; ++j) b[j] = ld8(Wp + (size_t)(16 * j) * 1024 + k0);
#pragma unroll
        for (int i = 0; i < 4; ++i)
#pragma unroll
            for (int j = 0; j < 2; ++j)
                acc[i][j] = __builtin_amdgcn_mfma_f32_16x16x32_bf16(a[i], b[j], acc[i][j], 0, 0, 0);
    }

#pragma unroll
    for (int i = 0; i < 4; ++i) {
#pragma unroll
        for (int j = 0; j < 2; ++j) {
            const int n = n_base + 16 * j + row;
#pragma unroll
            for (int r = 0; r < 4; ++r) {
                const int m = m_base + 16 * i + quad * 4 + r;
                if (FEATB) {
                    g_featb[(size_t)m * G4 + n] = acc[i][j][r] + bias[n];
                } else {
                    float v = acc[i][j][r] + g_featb[(size_t)(m & 255) * G4 + n];
                    BP(g_xg)[(size_t)m * G4 + n] = __float2bfloat16(v);
                }
            }
        }
    }
}

// =============================================================
// One LSTM timestep: gates = g_xg[tt] + h(t-1) @ Whh^T; cell update; mask.
// Grid (H/16=64, B/64=4); block 256 = 4 waves; wave g computes gate g for
// a 64(b) x 16(j) slice. Gates exchanged via LDS, then elementwise update.
// h state: read g_h[(t+1)&1] (skip if t==0 -> h=0), write g_h[t&1].
// layer 0: h also appended (bf16) to g_seq[t]. layer 1: h written f32 to out_t.
// =============================================================
__global__ __launch_bounds__(256) void lstm_step(
    const int* __restrict__ length,
    float* __restrict__ out_t,          // layer-1 only (else nullptr)
    int t, int tt, int layer)
{
    __shared__ float lds[4 * 64 * 16];   // [gate][local_b][local_j] 16 KB

    const int tid  = threadIdx.x;
    const int lane = tid & 63, g = tid >> 6;   // wave id == gate (i,f,g,o)
    const int row  = lane & 15, quad = lane >> 4;
    const int j0 = blockIdx.x * 16;
    const int b0 = blockIdx.y * 64;

    const __hip_bfloat16* Whh = BPc(g_Whh) + (size_t)layer * G4 * 1024;
    const __hip_bfloat16* h_in = (t > 0) ? BPc(g_h[(t + 1) & 1]) : nullptr;
    __hip_bfloat16* h_out = BP(g_h[t & 1]);

    f32x4 acc[4] = {};
    if (h_in) {
        const __hip_bfloat16* ap = h_in + (size_t)(b0 + row) * HH + quad * 8;
        const __hip_bfloat16* wp = Whh + (size_t)(g * HH + j0 + row) * HH + quad * 8;
        for (int k0 = 0; k0 < HH; k0 += 32) {
            bf16x8 bfrag = ld8(wp + k0);
#pragma unroll
            for (int i = 0; i < 4; ++i)
                acc[i] = __builtin_amdgcn_mfma_f32_16x16x32_bf16(
                    ld8(ap + (size_t)(16 * i) * HH + k0), bfrag, acc[i], 0, 0, 0);
        }
    }

    const __hip_bfloat16* xg = BPc(g_xg) + (size_t)tt * BB * G4;
#pragma unroll
    for (int i = 0; i < 4; ++i) {
#pragma unroll
        for (int r = 0; r < 4; ++r) {
            const int lb = 16 * i + quad * 4 + r;       // 0..63
            lds[(g * 64 + lb) * 16 + row] =
                acc[i][r] + (float)xg[(size_t)(b0 + lb) * G4 + g * HH + j0 + row];
        }
    }
    __syncthreads();

    for (int e = tid; e < 64 * 16; e += 256) {
        const int lb = e >> 4, lj = e & 15;
        const int b = b0 + lb, jj = j0 + lj;
        const float gi = lds[(0 * 64 + lb) * 16 + lj];
        const float gf = lds[(1 * 64 + lb) * 16 + lj];
        const float gg = lds[(2 * 64 + lb) * 16 + lj];
        const float go = lds[(3 * 64 + lb) * 16 + lj];

        const size_t idx = (size_t)b * HH + jj;
        float hv;
        if (t < length[b]) {
            const float c_old = g_c[idx];
            const float si = 1.0f / (1.0f + __expf(-gi));
            const float sf = 1.0f / (1.0f + __expf(-gf));
            const float so = 1.0f / (1.0f + __expf(-go));
            const float tg = tanhf(gg);
            const float c_new = sf * c_old + si * tg;
            g_c[idx] = c_new;
            hv = so * tanhf(c_new);
        } else {
            hv = h_in ? (float)h_in[idx] : 0.0f;   // frozen past sequence end
        }
        const __hip_bfloat16 hb = __float2bfloat16(hv);
        h_out[idx] = hb;
        if (layer == 0) BP(g_seq)[(size_t)t * BB * HH + idx] = hb;
        else            out_t[idx] = hv;
    }
}

// ---------------- small utility kernels ----------------
__global__ __launch_bounds__(256) void zero_c() {
    g_c[blockIdx.x * 256 + threadIdx.x] = 0.0f;
}
// h_n (f32 from bf16 state, pp = final ping-pong idx) and c_n (f32 copy)
__global__ __launch_bounds__(256) void finish_layer(float* __restrict__ hn,
                                                    float* __restrict__ cn)
{
    const int i = blockIdx.x * 256 + threadIdx.x;
    hn[i] = (float)BPc(g_h[(TT - 1) & 1])[i];
    cn[i] = g_c[i];
}

// =============================================================
// host launcher — kernel launches ONLY (graph-capture safe)
// =============================================================
extern "C" void kernel_launch(void* const* d_in, const int* in_sizes, int n_in,
                              void* d_out, int out_size, void* d_ws, size_t ws_size,
                              hipStream_t stream)
{
    const float* x        = (const float*)d_in[0];  // (T,B,D)   f32
    const float* features = (const float*)d_in[1];  // (B,F)     f32
    const float* Wih      = (const float*)d_in[2];  // (L,4H,D)  f32
    const float* Whh      = (const float*)d_in[3];  // (L,4H,H)  f32
    const float* Wfh      = (const float*)d_in[4];  // (L,4H,F)  f32
    const float* bvec     = (const float*)d_in[5];  // (L,4H)    f32
    const int*   length   = (const int*)d_in[6];    // (B,)      int
    float* out = (float*)d_out;                     // f32 outputs

    // ---- convert f32 inputs to bf16 staging (every call; inputs restored)
    const size_t nX = (size_t)TT * BB * DD;         // 16.78M
    const size_t nW = (size_t)2 * G4 * 1024;        // 8.39M each
    const size_t nF = (size_t)BB * 1024;            // 262K
    cvt_bf16<<<(int)(nX / 1024), 256, 0, stream>>>(0, x, nX);
    cvt_bf16<<<(int)(nW / 1024), 256, 0, stream>>>(1, Wih, nW);
    cvt_bf16<<<(int)(nW / 1024), 256, 0, stream>>>(2, Whh, nW);
    cvt_bf16<<<(int)(nW / 1024), 256, 0, stream>>>(3, Wfh, nW);
    cvt_bf16<<<(int)(nF / 1024), 256, 0, stream>>>(4, features, nF);

    float* out_hn = out + (size_t)TT * BB * HH;
    float* out_cn = out_hn + (size_t)2 * BB * HH;

    for (int l = 0; l < 2; ++l) {
        const size_t w_off = (size_t)l * G4 * 1024;

        // g_featb = feat @ Wfh[l]^T + b[l]   (f32 [B,4H])
        gemm_k<true><<<dim3(G4 / 64, BB / 128), 256, 0, stream>>>(
            0, w_off, bvec + (size_t)l * G4);
        zero_c<<<BB * HH / 256, 256, 0, stream>>>();

        for (int c0 = 0; c0 < TT; c0 += CHT) {
            // g_xg = g_seq[c0:c0+CHT] @ Wih[l]^T + g_featb  (bf16 [CHT*B,4H])
            // (layer 1: g_seq rows already replaced by layer-0 h sequence;
            //  each chunk is read here strictly before steps overwrite it)
            gemm_k<false><<<dim3(G4 / 64, CHT * BB / 128), 256, 0, stream>>>(
                (size_t)c0 * BB * DD, w_off, nullptr);

            for (int tt = 0; tt < CHT; ++tt) {
                const int t = c0 + tt;
                lstm_step<<<dim3(HH / 16, BB / 64), 256, 0, stream>>>(
                    length, out + (size_t)t * BB * HH, t, tt, l);
            }
        }

        finish_layer<<<BB * HH / 256, 256, 0, stream>>>(
            out_hn + (size_t)l * BB * HH, out_cn + (size_t)l * BB * HH);
    }
}